// Round 12
// baseline (118.623 us; speedup 1.0000x reference)
//
#include <hip/hip_runtime.h>
#include <cstdint>
#include <cstddef>

typedef unsigned short u16;
typedef __attribute__((ext_vector_type(8))) short bf16x8;
typedef __attribute__((ext_vector_type(4))) float f32x4;

#define S_LEN 4096

__device__ __forceinline__ float bf2f(u16 u) {
  return __uint_as_float(((unsigned)u) << 16);
}
__device__ __forceinline__ u16 f2bf(float f) {
  unsigned x = __float_as_uint(f);
  return (u16)((x + 0x7fffu + ((x >> 16) & 1u)) >> 16);
}
// packed RNE f32x2 -> bf16x2: low16 = a, high16 = b
__device__ __forceinline__ unsigned pk2(float a, float b) {
  unsigned r;
  asm("v_cvt_pk_bf16_f32 %0, %1, %2" : "=v"(r) : "v"(a), "v"(b));
  return r;
}

// ---------------------------------------------------------------------------
// TR-subtiled tile layout (4096 u16 = 8KB): element (r = contraction idx,
// x = preserved idx) at u16 index:
//   (x>>4)*1024 + (r>>5)*512 + ((r>>2)&1)*256 + ((r>>3)&3)*64 + (r&3)*16 + (x&15)
// Properties:
//  - producer with 4-consecutive-x runs (MFMA C d-runs) stores ushort4/b64
//  - fragment (a,ks,eh), lane (c=l&15, kg=l>>4): ds_read_b64_tr_b16 at elem
//    a*1024+ks*512+eh*256+kg*64+c yields j=0..3 -> r = ks*32+kg*8+eh*4+j, x=a*16+c
// ---------------------------------------------------------------------------
__device__ __forceinline__ int tst(int r, int x) {
  return ((x >> 4) << 10) + ((r >> 5) << 9) + (((r >> 2) & 1) << 8) +
         (((r >> 3) & 3) << 6) + ((r & 3) << 4) + (x & 15);
}
// digit part of tst for fixed r (tile-uniform)
__device__ __forceinline__ int rdig(int r) {
  return ((r >> 5) << 9) + (((r >> 2) & 1) << 8) + (((r >> 3) & 3) << 6) + ((r & 3) << 4);
}

// hardware transpose read: 4 bf16 at byte addr {p, p+32, p+64, p+96}
__device__ __forceinline__ uint2 trr(const ushort* p) {
  uint2 d;
  asm volatile("ds_read_b64_tr_b16 %0, %1" : "=v"(d) : "v"((unsigned)(uintptr_t)p));
  return d;
}

// pre-packed bf16 weight fragment: flat row = gr*16 + (lane&15), k = ks*32 + (lane>>4)*8 + e
__device__ __forceinline__ bf16x8 apk_frag(const u16* __restrict__ APK, int mat, int gr,
                                           int ks, int lane) {
  return *(const bf16x8*)&APK[(((((mat << 8) + gr) << 1) + ks) << 9) + lane * 8];
}

// ---- legacy XOR-swizzled tile helpers (K1 only; proven in round 5) ----
__device__ __forceinline__ int ltelem(int c, int r) {
  int swz = ((r >> 3) ^ (c & 7) ^ ((c >> 3) & 7)) & 7;
  return (c << 6) | (swz << 3) | (r & 7);
}
__device__ __forceinline__ bf16x8 tile_frag(const ushort* LT, int a, int ks, int lane) {
  int c = (a << 4) + (lane & 15);
  int kg = (ks << 2) + (lane >> 4);
  int base = (c << 6) | (((kg ^ (c & 7) ^ ((c >> 3) & 7)) & 7) << 3);
  return *(const bf16x8*)&LT[base];
}
__device__ __forceinline__ void mmT_old(const ushort* LT, const u16* __restrict__ APK,
                                        int mat, int gr, int lane, f32x4 acc[4]) {
#pragma unroll
  for (int ks = 0; ks < 2; ++ks) {
    bf16x8 bw = apk_frag(APK, mat, gr, ks, lane);
#pragma unroll
    for (int a = 0; a < 4; ++a) {
      bf16x8 at = tile_frag(LT, a, ks, lane);
      acc[a] = __builtin_amdgcn_mfma_f32_16x16x32_bf16(at, bw, acc[a], 0, 0, 0);
    }
  }
}

// ---- TR-layout mm: fragments via hardware transpose reads ----
// C[d=64 rows][16 cols]: acc[a] rows d = a*16 + (lane>>4)*4 + reg, col = gr*16 + (lane&15)
__device__ __forceinline__ void mmT_tr(const ushort* LT, const u16* __restrict__ APK,
                                       int mat, int gr, int lane, f32x4 acc[4]) {
  const ushort* base = LT + ((lane & 15) + ((lane >> 4) << 6));
  uint2 fr[4][2][2];
#pragma unroll
  for (int a = 0; a < 4; ++a)
#pragma unroll
    for (int ks = 0; ks < 2; ++ks)
#pragma unroll
      for (int eh = 0; eh < 2; ++eh)
        fr[a][ks][eh] = trr(base + (a << 10) + (ks << 9) + (eh << 8));
  asm volatile("s_waitcnt lgkmcnt(0)" ::: "memory");
  __builtin_amdgcn_sched_barrier(0);
#pragma unroll
  for (int ks = 0; ks < 2; ++ks) {
    bf16x8 bw = apk_frag(APK, mat, gr, ks, lane);
#pragma unroll
    for (int a = 0; a < 4; ++a) {
      union { uint2 u[2]; bf16x8 v; } cv;
      cv.u[0] = fr[a][ks][0];
      cv.u[1] = fr[a][ks][1];
      acc[a] = __builtin_amdgcn_mfma_f32_16x16x32_bf16(cv.v, bw, acc[a], 0, 0, 0);
    }
  }
}

// ---------------------------------------------------------------------------
// k_prep: pack {M1L,M1R,M2L,M2R} (fp32 64^3 row-major) into fragment order bf16.
// ---------------------------------------------------------------------------
__global__ __launch_bounds__(256) void k_prep(const float* __restrict__ W0,
                                              const float* __restrict__ W1,
                                              const float* __restrict__ W2,
                                              const float* __restrict__ W3,
                                              u16* __restrict__ APK) {
  const int gr = blockIdx.x, mat = blockIdx.y;
  const float* W = (mat == 0) ? W0 : (mat == 1) ? W1 : (mat == 2) ? W2 : W3;
  const int t = threadIdx.x;
  const int lane = t & 63, ks = (t >> 6) & 1, half = t >> 7;
  const int row = gr * 16 + (lane & 15);
  const int k0 = ks * 32 + ((lane >> 4) << 3) + half * 4;
  float4 v = *(const float4*)&W[row * 64 + k0];
  ushort4 o;
  o.x = f2bf(v.x); o.y = f2bf(v.y); o.z = f2bf(v.z); o.w = f2bf(v.w);
  *(ushort4*)&APK[((((((mat << 8) + gr) << 1) + ks) << 6) + lane) * 8 + half * 4] = o;
}

// ---------------------------------------------------------------------------
// K1: T1tile(n)[r=B][x=d] = sum_m L1[B][n][m] * q[b, m*64+B, h, d]
// grid (B=64, bh=64).  Body = proven round-5; only the store layout changed
// to the TR-subtiled T1 format.
// ---------------------------------------------------------------------------
__global__ __launch_bounds__(256) void k_m1(const float* __restrict__ q,
                                            const u16* __restrict__ APK,
                                            u16* __restrict__ T1) {
  const int B = blockIdx.x, bh = blockIdx.y;
  const int b = bh >> 3, h = bh & 7;
  __shared__ __align__(16) ushort LT[4096];          // (c=d, r=m), XOR-swizzled
  const int tid = threadIdx.x, w = tid >> 6, lane = tid & 63;
  {
    const int m = tid >> 2, ch = tid & 3;
    const float* qrow = q + ((((size_t)b * S_LEN + (size_t)m * 64 + B) * 8 + h) << 6);
#pragma unroll
    for (int i = 0; i < 4; ++i) {
      float4 v = *(const float4*)(qrow + ch * 16 + i * 4);
      int c0 = ch * 16 + i * 4;
      LT[ltelem(c0 + 0, m)] = f2bf(v.x);
      LT[ltelem(c0 + 1, m)] = f2bf(v.y);
      LT[ltelem(c0 + 2, m)] = f2bf(v.z);
      LT[ltelem(c0 + 3, m)] = f2bf(v.w);
    }
  }
  __syncthreads();
  f32x4 acc[4] = {};
  mmT_old(LT, APK, 0, B * 4 + w, lane, acc);         // C[d][n]
  const int n = (w << 4) + (lane & 15);
  const int dg = (lane >> 4) << 2;
  const int Bd = rdig(B);
  u16* dst = T1 + (((size_t)bh * 64 + n) << 12);
#pragma unroll
  for (int a = 0; a < 4; ++a) {
    ushort4 o;
    o.x = f2bf(acc[a][0]); o.y = f2bf(acc[a][1]);
    o.z = f2bf(acc[a][2]); o.w = f2bf(acc[a][3]);
    *(ushort4*)&dst[(a << 10) + Bd + dg] = o;
  }
}

// ---------------------------------------------------------------------------
// K2: per (bh, n):  mm(R1) -> *k + b1 -> mm(L2) -> T2tile(n2)[r=n][x=d]
// grid (n=64, bh=64).  TR layout: staging = raw b128 copy, frags = tr-reads,
// epilogue = b64 vector writes.
// ---------------------------------------------------------------------------
__global__ __launch_bounds__(256) void k_m2b(const u16* __restrict__ T1,
                                             const u16* __restrict__ APK,
                                             const float* __restrict__ keys,
                                             const float* __restrict__ b1,
                                             u16* __restrict__ T2) {
  const int n = blockIdx.x, bh = blockIdx.y;
  const int b = bh >> 3, h = bh & 7;
  __shared__ __align__(16) ushort LT[4096];    // T1 tile (by-B), raw copy
  __shared__ __align__(16) ushort LT2[4096];   // P tile (by-p)
  const int tid = threadIdx.x, w = tid >> 6, lane = tid & 63;
  const int p = (w << 4) + (lane & 15);
  const int dg = (lane >> 4) << 2;

  // issue-early: keys + bias for this lane's C positions
  const float b1v = b1[p * 64 + n];
  const float* krow = &keys[(((size_t)b * S_LEN + p * 64 + n) * 8 + h) << 6];
  float4 kreg[4];
#pragma unroll
  for (int a = 0; a < 4; ++a) kreg[a] = *(const float4*)(krow + (a << 4) + dg);

  // stage: raw 8KB copy (layout byte-identical to global tile)
  {
    const uint4* src = (const uint4*)(T1 + (((size_t)bh * 64 + n) << 12));
    uint4 v0 = src[tid], v1 = src[tid + 256];
    ((uint4*)LT)[tid] = v0;
    ((uint4*)LT)[tid + 256] = v1;
  }
  __syncthreads();

  f32x4 acc[4] = {};
  mmT_tr(LT, APK, 1, n * 4 + w, lane, acc);          // R1: C[d][p]
  const int pd = rdig(p);
#pragma unroll
  for (int a = 0; a < 4; ++a) {
    uint2 pw;
    pw.x = pk2(acc[a][0] * kreg[a].x + b1v, acc[a][1] * kreg[a].y + b1v);
    pw.y = pk2(acc[a][2] * kreg[a].z + b1v, acc[a][3] * kreg[a].w + b1v);
    *(uint2*)&LT2[(a << 10) + pd + dg] = pw;
  }
  __syncthreads();

  f32x4 acc2[4] = {};
  mmT_tr(LT2, APK, 2, n * 4 + w, lane, acc2);        // L2: C[d][n2]
  const int nd = rdig(n);
  u16* dst = T2 + (((size_t)bh * 64 + p) << 12);     // n2 = p position
#pragma unroll
  for (int a = 0; a < 4; ++a) {
    ushort4 o;
    o.x = f2bf(acc2[a][0]); o.y = f2bf(acc2[a][1]);
    o.z = f2bf(acc2[a][2]); o.w = f2bf(acc2[a][3]);
    *(ushort4*)&dst[(a << 10) + nd + dg] = o;
  }
}

// ---------------------------------------------------------------------------
// K3: per (bh, n'): mm(R2) -> (+b2)*v -> Yp[bh][n'][p][d] bf16 (k_tr format)
// grid (n'=64, bh=64).
// ---------------------------------------------------------------------------
__global__ __launch_bounds__(256) void k_m3b(const u16* __restrict__ T2,
                                             const u16* __restrict__ APK,
                                             const float* __restrict__ vals,
                                             const float* __restrict__ b2,
                                             u16* __restrict__ Yp) {
  const int np = blockIdx.x, bh = blockIdx.y;
  const int b = bh >> 3, h = bh & 7;
  __shared__ __align__(16) ushort LT[4096];    // T2 tile (by-n), raw copy
  const int tid = threadIdx.x, w = tid >> 6, lane = tid & 63;
  const int p = (w << 4) + (lane & 15);
  const int dg = (lane >> 4) << 2;

  const float b2v = b2[p * 64 + np];
  const float* vrow = &vals[(((size_t)b * S_LEN + p * 64 + np) * 8 + h) << 6];
  float4 vreg[4];
#pragma unroll
  for (int a = 0; a < 4; ++a) vreg[a] = *(const float4*)(vrow + (a << 4) + dg);

  {
    const uint4* src = (const uint4*)(T2 + (((size_t)bh * 64 + np) << 12));
    uint4 v0 = src[tid], v1 = src[tid + 256];
    ((uint4*)LT)[tid] = v0;
    ((uint4*)LT)[tid + 256] = v1;
  }
  __syncthreads();

  f32x4 acc[4] = {};
  mmT_tr(LT, APK, 3, np * 4 + w, lane, acc);         // R2: C[d][p']
#pragma unroll
  for (int a = 0; a < 4; ++a) {
    int d0 = (a << 4) + dg;
    ushort4 o;
    o.x = f2bf((acc[a][0] + b2v) * vreg[a].x);
    o.y = f2bf((acc[a][1] + b2v) * vreg[a].y);
    o.z = f2bf((acc[a][2] + b2v) * vreg[a].z);
    o.w = f2bf((acc[a][3] + b2v) * vreg[a].w);
    *(ushort4*)&Yp[(((size_t)bh * 64 + np) * 64 + p) * 64 + d0] = o;
  }
}

// ---------------------------------------------------------------------------
// K4: out[bh][d][p*64+np] = Yp[bh][np][p][d]  (fp32, coalesced both sides)
// ---------------------------------------------------------------------------
__global__ __launch_bounds__(256) void k_tr(const u16* __restrict__ Yp,
                                            float* __restrict__ out) {
  const int p = blockIdx.x, bh = blockIdx.y;
  __shared__ __align__(16) ushort YT[4096];    // (c=np, r=d)
  const int tid = threadIdx.x;
#pragma unroll
  for (int i = 0; i < 2; ++i) {
    int idx = i * 256 + tid;
    int np = idx >> 3, q8 = idx & 7;   // d0 = q8*8
    uint4 vv = *(const uint4*)&Yp[(((size_t)bh * 64 + np) * 64 + p) * 64 + q8 * 8];
    *(uint4*)&YT[ltelem(np, q8 * 8)] = vv;
  }
  __syncthreads();
#pragma unroll
  for (int i = 0; i < 4; ++i) {
    int idx = i * 256 + tid;
    int d = idx >> 4, np0 = (idx & 15) * 4;
    float4 o;
    o.x = bf2f(YT[ltelem(np0 + 0, d)]);
    o.y = bf2f(YT[ltelem(np0 + 1, d)]);
    o.z = bf2f(YT[ltelem(np0 + 2, d)]);
    o.w = bf2f(YT[ltelem(np0 + 3, d)]);
    *(float4*)&out[((size_t)bh * 64 + d) * S_LEN + p * 64 + np0] = o;
  }
}

// ---------------------------------------------------------------------------
extern "C" void kernel_launch(void* const* d_in, const int* in_sizes, int n_in,
                              void* d_out, int out_size, void* d_ws, size_t ws_size,
                              hipStream_t stream) {
  const float* q   = (const float*)d_in[0];
  const float* k   = (const float*)d_in[1];
  const float* v   = (const float*)d_in[2];
  const float* M1L = (const float*)d_in[3];
  const float* M1R = (const float*)d_in[4];
  const float* M2L = (const float*)d_in[5];
  const float* M2R = (const float*)d_in[6];
  const float* b1  = (const float*)d_in[7];
  const float* b2  = (const float*)d_in[8];

  u16* T1 = (u16*)d_ws;
  u16* T2 = T1 + (size_t)64 * 64 * 64 * 64;  // 32 MB each
  u16* Yp = T1;                              // T1 dead after K2 — reuse
  // Apack (2 MB) in the head of d_out; k_tr (final kernel) rewrites all of d_out.
  u16* APK = (u16*)d_out;

  dim3 blk(256);
  dim3 grd(64, 64);
  k_prep<<<dim3(256, 4), blk, 0, stream>>>(M1L, M1R, M2L, M2R, APK);
  k_m1 <<<grd, blk, 0, stream>>>(q, APK, T1);
  k_m2b<<<grd, blk, 0, stream>>>(T1, APK, k, b1, T2);
  k_m3b<<<grd, blk, 0, stream>>>(T2, APK, v, b2, Yp);
  k_tr <<<grd, blk, 0, stream>>>(Yp, (float*)d_out);
}

// Round 13
// 114.965 us; speedup vs baseline: 1.0318x; 1.0318x over previous
//
#include <hip/hip_runtime.h>
#include <cstdint>
#include <cstddef>

typedef unsigned short u16;
typedef __attribute__((ext_vector_type(8))) short bf16x8;
typedef __attribute__((ext_vector_type(4))) float f32x4;

#define S_LEN 4096

__device__ __forceinline__ float bf2f(u16 u) {
  return __uint_as_float(((unsigned)u) << 16);
}
__device__ __forceinline__ u16 f2bf(float f) {
  unsigned x = __float_as_uint(f);
  return (u16)((x + 0x7fffu + ((x >> 16) & 1u)) >> 16);
}
// packed RNE f32x2 -> bf16x2: low16 = a, high16 = b
__device__ __forceinline__ unsigned pk2(float a, float b) {
  unsigned r;
  asm("v_cvt_pk_bf16_f32 %0, %1, %2" : "=v"(r) : "v"(a), "v"(b));
  return r;
}

// ---------------------------------------------------------------------------
// TR-subtiled tile layout (4096 u16 = 8KB): element (r = contraction idx,
// x = preserved idx) at u16 index:
//   (x>>4)*1024 + (r>>5)*512 + ((r>>2)&1)*256 + ((r>>3)&3)*64 + (r&3)*16 + (x&15)
// Properties:
//  - a 16-long x-run at fixed r is CONTIGUOUS (32 B) -> vector stores/stage
//  - fragment (a,ks,eh), lane (c=l&15, kg=l>>4): ds_read_b64_tr_b16 at elem
//    a*1024+ks*512+eh*256+kg*64+c yields j=0..3 -> r = ks*32+kg*8+eh*4+j, x=a*16+c
// ---------------------------------------------------------------------------
__device__ __forceinline__ int rdig(int r) {
  return ((r >> 5) << 9) + (((r >> 2) & 1) << 8) + (((r >> 3) & 3) << 6) + ((r & 3) << 4);
}

// hardware transpose read: 4 bf16 at byte addr {p, p+32, p+64, p+96}
__device__ __forceinline__ uint2 trr(const ushort* p) {
  uint2 d;
  asm volatile("ds_read_b64_tr_b16 %0, %1" : "=v"(d) : "v"((unsigned)(uintptr_t)p));
  return d;
}

// pre-packed bf16 weight fragment: flat row = gr*16 + (lane&15), k = ks*32 + (lane>>4)*8 + e
__device__ __forceinline__ bf16x8 apk_frag(const u16* __restrict__ APK, int mat, int gr,
                                           int ks, int lane) {
  return *(const bf16x8*)&APK[(((((mat << 8) + gr) << 1) + ks) << 9) + lane * 8];
}

// ---- TR-layout mm: fragments via hardware transpose reads ----
// C[d=64 rows][16 cols]: acc[a] rows d = a*16 + (lane>>4)*4 + reg, col = gr*16 + (lane&15)
__device__ __forceinline__ void mmT_tr(const ushort* LT, const u16* __restrict__ APK,
                                       int mat, int gr, int lane, f32x4 acc[4]) {
  const ushort* base = LT + ((lane & 15) + ((lane >> 4) << 6));
  uint2 fr[4][2][2];
#pragma unroll
  for (int a = 0; a < 4; ++a)
#pragma unroll
    for (int ks = 0; ks < 2; ++ks)
#pragma unroll
      for (int eh = 0; eh < 2; ++eh)
        fr[a][ks][eh] = trr(base + (a << 10) + (ks << 9) + (eh << 8));
  asm volatile("s_waitcnt lgkmcnt(0)" ::: "memory");
  __builtin_amdgcn_sched_barrier(0);
#pragma unroll
  for (int ks = 0; ks < 2; ++ks) {
    bf16x8 bw = apk_frag(APK, mat, gr, ks, lane);
#pragma unroll
    for (int a = 0; a < 4; ++a) {
      union { uint2 u[2]; bf16x8 v; } cv;
      cv.u[0] = fr[a][ks][0];
      cv.u[1] = fr[a][ks][1];
      acc[a] = __builtin_amdgcn_mfma_f32_16x16x32_bf16(cv.v, bw, acc[a], 0, 0, 0);
    }
  }
}

// ---- legacy XOR-swizzled tile helpers (k_tr only) ----
__device__ __forceinline__ int ltelem(int c, int r) {
  int swz = ((r >> 3) ^ (c & 7) ^ ((c >> 3) & 7)) & 7;
  return (c << 6) | (swz << 3) | (r & 7);
}

// ---------------------------------------------------------------------------
// k_prep: pack {M1L,M1R,M2L,M2R} (fp32 64^3 row-major) into fragment order bf16.
// ---------------------------------------------------------------------------
__global__ __launch_bounds__(256) void k_prep(const float* __restrict__ W0,
                                              const float* __restrict__ W1,
                                              const float* __restrict__ W2,
                                              const float* __restrict__ W3,
                                              u16* __restrict__ APK) {
  const int gr = blockIdx.x, mat = blockIdx.y;
  const float* W = (mat == 0) ? W0 : (mat == 1) ? W1 : (mat == 2) ? W2 : W3;
  const int t = threadIdx.x;
  const int lane = t & 63, ks = (t >> 6) & 1, half = t >> 7;
  const int row = gr * 16 + (lane & 15);
  const int k0 = ks * 32 + ((lane >> 4) << 3) + half * 4;
  float4 v = *(const float4*)&W[row * 64 + k0];
  ushort4 o;
  o.x = f2bf(v.x); o.y = f2bf(v.y); o.z = f2bf(v.z); o.w = f2bf(v.w);
  *(ushort4*)&APK[((((((mat << 8) + gr) << 1) + ks) << 6) + lane) * 8 + half * 4] = o;
}

// ---------------------------------------------------------------------------
// K1: T1tile(n)[r=B][x=d] = sum_m L1[B][n][m] * q[b, m*64+B, h, d]
// grid (B=64, bh=64).  TR-native staging: thread (m=tid>>2, ch=tid&3) reads
// 16 consecutive d of row s=m*64+B, pk2-packs, writes ONE contiguous 32B run
// at LT[(ch<<10)+rdig(m)].  Fragments via tr-reads (contraction r = m).
// ---------------------------------------------------------------------------
__global__ __launch_bounds__(256) void k_m1(const float* __restrict__ q,
                                            const u16* __restrict__ APK,
                                            u16* __restrict__ T1) {
  const int B = blockIdx.x, bh = blockIdx.y;
  const int b = bh >> 3, h = bh & 7;
  __shared__ __align__(16) ushort LT[4096];
  const int tid = threadIdx.x, w = tid >> 6, lane = tid & 63;
  {
    const int m = tid >> 2, ch = tid & 3;
    const float* qrow = q + ((((size_t)b * S_LEN + (size_t)m * 64 + B) * 8 + h) << 6) + ch * 16;
    float4 v0 = ((const float4*)qrow)[0];
    float4 v1 = ((const float4*)qrow)[1];
    float4 v2 = ((const float4*)qrow)[2];
    float4 v3 = ((const float4*)qrow)[3];
    uint4 p0, p1;
    p0.x = pk2(v0.x, v0.y); p0.y = pk2(v0.z, v0.w);
    p0.z = pk2(v1.x, v1.y); p0.w = pk2(v1.z, v1.w);
    p1.x = pk2(v2.x, v2.y); p1.y = pk2(v2.z, v2.w);
    p1.z = pk2(v3.x, v3.y); p1.w = pk2(v3.z, v3.w);
    u16* dst = LT + (ch << 10) + rdig(m);
    *(uint4*)dst = p0;
    *(uint4*)(dst + 8) = p1;
  }
  __syncthreads();
  f32x4 acc[4] = {};
  mmT_tr(LT, APK, 0, B * 4 + w, lane, acc);          // C[d][n]
  const int dg = (lane >> 4) << 2;
  const int n = (w << 4) + (lane & 15);
  const int Bd = rdig(B);
  u16* dst = T1 + (((size_t)bh * 64 + n) << 12);
#pragma unroll
  for (int a = 0; a < 4; ++a) {
    ushort4 o;
    o.x = f2bf(acc[a][0]); o.y = f2bf(acc[a][1]);
    o.z = f2bf(acc[a][2]); o.w = f2bf(acc[a][3]);
    *(ushort4*)&dst[(a << 10) + Bd + dg] = o;
  }
}

// ---------------------------------------------------------------------------
// K2: per (bh, n-pair):  mm(R1) -> *k + b1 -> mm(L2) -> T2tile(n2)[r=n][x=d]
// grid (npair=32, bh=64).  2 tiles per flat block: all global loads issued
// upfront, 2 barriers TOTAL (amortized), mms interleave for ILP.
// ---------------------------------------------------------------------------
__global__ __launch_bounds__(256) void k_m2b(const u16* __restrict__ T1,
                                             const u16* __restrict__ APK,
                                             const float* __restrict__ keys,
                                             const float* __restrict__ b1,
                                             u16* __restrict__ T2) {
  const int n0 = blockIdx.x << 1, bh = blockIdx.y;
  const int b = bh >> 3, h = bh & 7;
  __shared__ __align__(16) ushort LT[2][4096];    // T1 tiles (by-B), raw copies
  __shared__ __align__(16) ushort LT2[2][4096];   // P tiles (by-p)
  const int tid = threadIdx.x, w = tid >> 6, lane = tid & 63;
  const int p = (w << 4) + (lane & 15);
  const int dg = (lane >> 4) << 2;

  // issue ALL global loads upfront (T1 tiles + keys + bias for both n)
  uint4 s00, s01, s10, s11;
  {
    const uint4* src0 = (const uint4*)(T1 + (((size_t)bh * 64 + n0) << 12));
    const uint4* src1 = (const uint4*)(T1 + (((size_t)bh * 64 + n0 + 1) << 12));
    s00 = src0[tid]; s01 = src0[tid + 256];
    s10 = src1[tid]; s11 = src1[tid + 256];
  }
  float4 kreg[2][4];
  float b1v[2];
#pragma unroll
  for (int t = 0; t < 2; ++t) {
    const int n = n0 + t;
    b1v[t] = b1[p * 64 + n];
    const float* krow = &keys[(((size_t)b * S_LEN + p * 64 + n) * 8 + h) << 6];
#pragma unroll
    for (int a = 0; a < 4; ++a) kreg[t][a] = *(const float4*)(krow + (a << 4) + dg);
  }
  ((uint4*)LT[0])[tid] = s00; ((uint4*)LT[0])[tid + 256] = s01;
  ((uint4*)LT[1])[tid] = s10; ((uint4*)LT[1])[tid + 256] = s11;
  __syncthreads();

  const int pd = rdig(p);
#pragma unroll
  for (int t = 0; t < 2; ++t) {
    const int n = n0 + t;
    f32x4 acc[4] = {};
    mmT_tr(LT[t], APK, 1, n * 4 + w, lane, acc);     // R1: C[d][p]
#pragma unroll
    for (int a = 0; a < 4; ++a) {
      uint2 pw;
      pw.x = pk2(acc[a][0] * kreg[t][a].x + b1v[t], acc[a][1] * kreg[t][a].y + b1v[t]);
      pw.y = pk2(acc[a][2] * kreg[t][a].z + b1v[t], acc[a][3] * kreg[t][a].w + b1v[t]);
      *(uint2*)&LT2[t][(a << 10) + pd + dg] = pw;
    }
  }
  __syncthreads();

  u16* dst = T2 + (((size_t)bh * 64 + p) << 12);     // n2 = p position
#pragma unroll
  for (int t = 0; t < 2; ++t) {
    const int n = n0 + t;
    f32x4 acc2[4] = {};
    mmT_tr(LT2[t], APK, 2, n * 4 + w, lane, acc2);   // L2: C[d][n2]
    const int nd = rdig(n);
#pragma unroll
    for (int a = 0; a < 4; ++a) {
      ushort4 o;
      o.x = f2bf(acc2[a][0]); o.y = f2bf(acc2[a][1]);
      o.z = f2bf(acc2[a][2]); o.w = f2bf(acc2[a][3]);
      *(ushort4*)&dst[(a << 10) + nd + dg] = o;
    }
  }
}

// ---------------------------------------------------------------------------
// K3: per (bh, n'): mm(R2) -> (+b2)*v -> Yp[bh][n'][p][d] bf16 (k_tr format)
// grid (n'=64, bh=64).
// ---------------------------------------------------------------------------
__global__ __launch_bounds__(256) void k_m3b(const u16* __restrict__ T2,
                                             const u16* __restrict__ APK,
                                             const float* __restrict__ vals,
                                             const float* __restrict__ b2,
                                             u16* __restrict__ Yp) {
  const int np = blockIdx.x, bh = blockIdx.y;
  const int b = bh >> 3, h = bh & 7;
  __shared__ __align__(16) ushort LT[4096];    // T2 tile (by-n), raw copy
  const int tid = threadIdx.x, w = tid >> 6, lane = tid & 63;
  const int p = (w << 4) + (lane & 15);
  const int dg = (lane >> 4) << 2;

  const float b2v = b2[p * 64 + np];
  const float* vrow = &vals[(((size_t)b * S_LEN + p * 64 + np) * 8 + h) << 6];
  float4 vreg[4];
#pragma unroll
  for (int a = 0; a < 4; ++a) vreg[a] = *(const float4*)(vrow + (a << 4) + dg);

  {
    const uint4* src = (const uint4*)(T2 + (((size_t)bh * 64 + np) << 12));
    uint4 v0 = src[tid], v1 = src[tid + 256];
    ((uint4*)LT)[tid] = v0;
    ((uint4*)LT)[tid + 256] = v1;
  }
  __syncthreads();

  f32x4 acc[4] = {};
  mmT_tr(LT, APK, 3, np * 4 + w, lane, acc);         // R2: C[d][p']
#pragma unroll
  for (int a = 0; a < 4; ++a) {
    int d0 = (a << 4) + dg;
    ushort4 o;
    o.x = f2bf((acc[a][0] + b2v) * vreg[a].x);
    o.y = f2bf((acc[a][1] + b2v) * vreg[a].y);
    o.z = f2bf((acc[a][2] + b2v) * vreg[a].z);
    o.w = f2bf((acc[a][3] + b2v) * vreg[a].w);
    *(ushort4*)&Yp[(((size_t)bh * 64 + np) * 64 + p) * 64 + d0] = o;
  }
}

// ---------------------------------------------------------------------------
// K4: out[bh][d][p*64+np] = Yp[bh][np][p][d]  (fp32, coalesced both sides)
// ---------------------------------------------------------------------------
__global__ __launch_bounds__(256) void k_tr(const u16* __restrict__ Yp,
                                            float* __restrict__ out) {
  const int p = blockIdx.x, bh = blockIdx.y;
  __shared__ __align__(16) ushort YT[4096];    // (c=np, r=d)
  const int tid = threadIdx.x;
#pragma unroll
  for (int i = 0; i < 2; ++i) {
    int idx = i * 256 + tid;
    int np = idx >> 3, q8 = idx & 7;   // d0 = q8*8
    uint4 vv = *(const uint4*)&Yp[(((size_t)bh * 64 + np) * 64 + p) * 64 + q8 * 8];
    *(uint4*)&YT[ltelem(np, q8 * 8)] = vv;
  }
  __syncthreads();
#pragma unroll
  for (int i = 0; i < 4; ++i) {
    int idx = i * 256 + tid;
    int d = idx >> 4, np0 = (idx & 15) * 4;
    float4 o;
    o.x = bf2f(YT[ltelem(np0 + 0, d)]);
    o.y = bf2f(YT[ltelem(np0 + 1, d)]);
    o.z = bf2f(YT[ltelem(np0 + 2, d)]);
    o.w = bf2f(YT[ltelem(np0 + 3, d)]);
    *(float4*)&out[((size_t)bh * 64 + d) * S_LEN + p * 64 + np0] = o;
  }
}

// ---------------------------------------------------------------------------
extern "C" void kernel_launch(void* const* d_in, const int* in_sizes, int n_in,
                              void* d_out, int out_size, void* d_ws, size_t ws_size,
                              hipStream_t stream) {
  const float* q   = (const float*)d_in[0];
  const float* k   = (const float*)d_in[1];
  const float* v   = (const float*)d_in[2];
  const float* M1L = (const float*)d_in[3];
  const float* M1R = (const float*)d_in[4];
  const float* M2L = (const float*)d_in[5];
  const float* M2R = (const float*)d_in[6];
  const float* b1  = (const float*)d_in[7];
  const float* b2  = (const float*)d_in[8];

  u16* T1 = (u16*)d_ws;
  u16* T2 = T1 + (size_t)64 * 64 * 64 * 64;  // 32 MB each
  u16* Yp = T1;                              // T1 dead after K2 — reuse
  // Apack (2 MB) in the head of d_out; k_tr (final kernel) rewrites all of d_out.
  u16* APK = (u16*)d_out;

  dim3 blk(256);
  k_prep<<<dim3(256, 4), blk, 0, stream>>>(M1L, M1R, M2L, M2R, APK);
  k_m1 <<<dim3(64, 64), blk, 0, stream>>>(q, APK, T1);
  k_m2b<<<dim3(32, 64), blk, 0, stream>>>(T1, APK, k, b1, T2);
  k_m3b<<<dim3(64, 64), blk, 0, stream>>>(T2, APK, v, b2, Yp);
  k_tr <<<dim3(64, 64), blk, 0, stream>>>(Yp, (float*)d_out);
}